// Round 3
// baseline (269.834 us; speedup 1.0000x reference)
//
#include <hip/hip_runtime.h>

// Problem: B=1, L=2048, DIM=16, HEADS=1, DIM_HEAD=1 (INNER=1).
// softmax over the size-1 heads axis == 1.0 -> attention is all-ones, q/k dead.
// out[0,i,j,d] = v[i]*W_out[d,0] + b_out[d], independent of j,
// where v[i] = x[i,:] . W_qkv[2,:]  (third projection row).
// => per row i: compute one scalar v, broadcast-fill 128 KiB. Total 256 MiB
// of pure writes; floor ~41 us at the 6.6 TB/s this box's memset achieves.

#define L_SEQ 2048
#define DIM 16

// Native clang vector type: __builtin_nontemporal_store rejects HIP's
// float4 class wrapper but accepts vectors-of-float.
typedef float f32x4 __attribute__((ext_vector_type(4)));

// One block per row i. Each thread computes v redundantly (broadcast loads,
// 16 FMAs), builds its d-group's float4, then 32 non-temporal 16B stores.
// Row span = 2048*16 floats = 8192 float4 = 128 KiB; 256 threads -> 32 iters.
__global__ void __launch_bounds__(256) attn_bcast_fill(
    const float* __restrict__ x,
    const float* __restrict__ W_qkv,
    const float* __restrict__ W_out,
    const float* __restrict__ b_out,
    f32x4* __restrict__ out) {
    const int i = blockIdx.x;
    const int t = threadIdx.x;
    const int dg = t & 3;  // which float4 of the 16-wide d dimension

    // v = dot(x[i,:], W_qkv[2,:]) -- x row is 64 B, float4-aligned.
    const f32x4* xr = (const f32x4*)(x + (size_t)i * DIM);
    const f32x4* wv = (const f32x4*)(W_qkv + 2 * DIM);
    float v = 0.f;
#pragma unroll
    for (int c = 0; c < 4; ++c) {
        f32x4 a = xr[c];
        f32x4 w = wv[c];
        v += a.x * w.x + a.y * w.y + a.z * w.z + a.w * w.w;
    }

    f32x4 val;
    val.x = v * W_out[4 * dg + 0] + b_out[4 * dg + 0];
    val.y = v * W_out[4 * dg + 1] + b_out[4 * dg + 1];
    val.z = v * W_out[4 * dg + 2] + b_out[4 * dg + 2];
    val.w = v * W_out[4 * dg + 3] + b_out[4 * dg + 3];

    f32x4* row_out = out + (size_t)i * (L_SEQ * DIM / 4);
#pragma unroll
    for (int k = 0; k < (L_SEQ * DIM / 4) / 256; ++k) {  // 32 stores
        __builtin_nontemporal_store(val, &row_out[t + k * 256]);
    }
}

extern "C" void kernel_launch(void* const* d_in, const int* in_sizes, int n_in,
                              void* d_out, int out_size, void* d_ws, size_t ws_size,
                              hipStream_t stream) {
    const float* x     = (const float*)d_in[0];  // (1, 2048, 16)
    const float* W_qkv = (const float*)d_in[1];  // (3, 16)
    const float* W_out = (const float*)d_in[2];  // (16, 1)
    const float* b_out = (const float*)d_in[3];  // (16,)
    attn_bcast_fill<<<L_SEQ, 256, 0, stream>>>(x, W_qkv, W_out, b_out,
                                               (f32x4*)d_out);
}